// Round 1
// 218.639 us; speedup vs baseline: 1.2056x; 1.2056x over previous
//
#include <hip/hip_runtime.h>
#include <hip/hip_bf16.h>

#define H 256
#define L2H 512
#define MAXLEN 256
#define NLAYERS 4
#define VOCAB 50257

// d_out layout: logp[50257], hidden_new[4*256], attn_weights[256]  (dtype = flag)
#define OUT_LOGP 0
#define OUT_HID  50257
#define OUT_ATTN 51281

// ws layout (fp32 elements) — 2305 floats = 9220 B
#define WS_SCORE  0       // 256 attn scores
#define WS_SM     256     // 256 softmax'd attn weights
#define WS_APP    512     // 256 attn_applied accumulator
#define WS_X0     768     // 256
#define WS_X1     1024    // 256
#define WS_PM     1280    // 512 per-block running max
#define WS_PS     1792    // 512 per-block running sum
#define WS_FLAG   2304    // 1.0f => inputs are bf16 ; 0.0f => inputs are fp32

// k_logits geometry: 512 blocks x 4 waves x 2 half-waves = 4096 concurrent rows
#define LOGITS_BLOCKS 512
#define LOGITS_STRIDE 4096

typedef unsigned short u16;

__device__ __forceinline__ float bf2f(u16 u) {
    return __uint_as_float(((unsigned int)u) << 16);
}

__device__ __forceinline__ u16 f2bf(float f) {
    unsigned int x = __float_as_uint(f);
    unsigned int r = x + 0x7fff + ((x >> 16) & 1);
    return (u16)(r >> 16);
}

// ---- dtype-polymorphic load/store helpers ----
template<bool BF16>
__device__ __forceinline__ float ld1(const void* p, size_t i) {
    if (BF16) return bf2f(((const u16*)p)[i]);
    else      return ((const float*)p)[i];
}

template<bool BF16>
__device__ __forceinline__ float4 ld4(const void* p, size_t i) {
    if (BF16) {
        ushort4 w = *(const ushort4*)((const u16*)p + i);
        return make_float4(bf2f(w.x), bf2f(w.y), bf2f(w.z), bf2f(w.w));
    } else {
        return *(const float4*)((const float*)p + i);
    }
}

template<bool BF16>
__device__ __forceinline__ void ld8(const void* p, size_t i, float* f) {
    if (BF16) {
        uint4 u = *(const uint4*)((const u16*)p + i);
        f[0] = bf2f(u.x & 0xffff); f[1] = bf2f(u.x >> 16);
        f[2] = bf2f(u.y & 0xffff); f[3] = bf2f(u.y >> 16);
        f[4] = bf2f(u.z & 0xffff); f[5] = bf2f(u.z >> 16);
        f[6] = bf2f(u.w & 0xffff); f[7] = bf2f(u.w >> 16);
    } else {
        const float4* q = (const float4*)((const float*)p + i);
        float4 a = q[0], b = q[1];
        f[0] = a.x; f[1] = a.y; f[2] = a.z; f[3] = a.w;
        f[4] = b.x; f[5] = b.y; f[6] = b.z; f[7] = b.w;
    }
}

template<bool BF16>
__device__ __forceinline__ void st(void* p, size_t i, float v) {
    if (BF16) ((u16*)p)[i] = f2bf(v);
    else      ((float*)p)[i] = v;
}

// ---------------- K0: sniff dtype of float inputs ----------------
__global__ __launch_bounds__(64) void k_sniff(const void* emb, float* ws) {
    int lane = threadIdx.x;
    float b = fabsf(bf2f(((const u16*)emb)[lane]));
    #pragma unroll
    for (int off = 32; off; off >>= 1) b = fmaxf(b, __shfl_xor(b, off));
    if (lane == 0) ws[WS_FLAG] = (b < 1.0f) ? 1.0f : 0.0f;
}

// ---------------- K1: attn scores = attn_in @ attn_w.T + attn_b ----------------
template<bool BF16>
__global__ __launch_bounds__(64) void k_attn_score(
    const int* __restrict__ tok, const void* __restrict__ emb,
    const void* __restrict__ hidden, const void* __restrict__ attn_w,
    const void* __restrict__ attn_b, float* __restrict__ ws)
{
    if ((ws[WS_FLAG] > 0.5f) != BF16) return;
    int lane = threadIdx.x;
    int j8 = lane * 8;
    float xin[8];
    if (lane < 32) ld8<BF16>(emb, (size_t)tok[0] * H + j8, xin);
    else           ld8<BF16>(hidden, (size_t)(j8 - H), xin);   // hidden[0]
    for (int k = 0; k < 8; ++k) {
        int r = blockIdx.x * 8 + k;
        float wf[8]; ld8<BF16>(attn_w, (size_t)r * L2H + j8, wf);
        float v = 0.f;
        #pragma unroll
        for (int q = 0; q < 8; ++q) v += xin[q] * wf[q];
        #pragma unroll
        for (int off = 32; off; off >>= 1) v += __shfl_xor(v, off);
        if (lane == 0) ws[WS_SCORE + r] = v + ld1<BF16>(attn_b, r);
    }
}

// ---------------- K2: softmax over 256 scores; zero attn_applied ----------------
template<bool BF16>
__global__ __launch_bounds__(256) void k_softmax(
    float* __restrict__ ws, void* __restrict__ out)
{
    if ((ws[WS_FLAG] > 0.5f) != BF16) return;
    __shared__ float red[256];
    int t = threadIdx.x;
    float s = ws[WS_SCORE + t];
    red[t] = s; __syncthreads();
    for (int off = 128; off; off >>= 1) {
        if (t < off) red[t] = fmaxf(red[t], red[t + off]);
        __syncthreads();
    }
    float M = red[0]; __syncthreads();
    float e = __expf(s - M);
    red[t] = e; __syncthreads();
    for (int off = 128; off; off >>= 1) {
        if (t < off) red[t] += red[t + off];
        __syncthreads();
    }
    float w = e / red[0];
    ws[WS_SM + t] = w;
    ws[WS_APP + t] = 0.f;
    st<BF16>(out, OUT_ATTN + t, w);
}

// ---------------- K3: attn_applied = attn_weights @ encoder_outputs ----------------
template<bool BF16>
__global__ __launch_bounds__(256) void k_attn_apply(
    const void* __restrict__ enc, float* __restrict__ ws)
{
    if ((ws[WS_FLAG] > 0.5f) != BF16) return;
    int t = threadIdx.x;
    int l0 = blockIdx.x * 16;
    float acc = 0.f;
    for (int l = l0; l < l0 + 16; ++l)
        acc += ws[WS_SM + l] * ld1<BF16>(enc, (size_t)l * H + t);
    atomicAdd(&ws[WS_APP + t], acc);
}

// ---------------- K4: x = relu(comb_in @ comb_w.T + comb_b) ----------------
template<bool BF16>
__global__ __launch_bounds__(64) void k_comb(
    const int* __restrict__ tok, const void* __restrict__ emb,
    const void* __restrict__ comb_w, const void* __restrict__ comb_b,
    float* __restrict__ ws)
{
    if ((ws[WS_FLAG] > 0.5f) != BF16) return;
    int lane = threadIdx.x;
    int j8 = lane * 8;
    float xin[8];
    if (lane < 32) {
        ld8<BF16>(emb, (size_t)tok[0] * H + j8, xin);
    } else {
        const float4* p = (const float4*)(ws + WS_APP + (j8 - H));
        float4 a = p[0], b = p[1];
        xin[0] = a.x; xin[1] = a.y; xin[2] = a.z; xin[3] = a.w;
        xin[4] = b.x; xin[5] = b.y; xin[6] = b.z; xin[7] = b.w;
    }
    for (int k = 0; k < 8; ++k) {
        int r = blockIdx.x * 8 + k;
        float wf[8]; ld8<BF16>(comb_w, (size_t)r * L2H + j8, wf);
        float v = 0.f;
        #pragma unroll
        for (int q = 0; q < 8; ++q) v += xin[q] * wf[q];
        #pragma unroll
        for (int off = 32; off; off >>= 1) v += __shfl_xor(v, off);
        if (lane == 0) ws[WS_X0 + r] = fmaxf(v + ld1<BF16>(comb_b, r), 0.f);
    }
}

// ---------------- K5: one GRU layer (PyTorch gate order r,z,n) ----------------
template<bool BF16>
__global__ __launch_bounds__(64) void k_gru(
    const void* __restrict__ wih, const void* __restrict__ whh,
    const void* __restrict__ bih, const void* __restrict__ bhh,
    const void* __restrict__ hprev, const float* __restrict__ xin,
    float* __restrict__ xout, void* __restrict__ hout, const float* __restrict__ ws)
{
    if ((ws[WS_FLAG] > 0.5f) != BF16) return;
    int lane = threadIdx.x;
    int e4 = lane * 4;
    float4 xv = *(const float4*)(xin + e4);
    float4 hv = ld4<BF16>(hprev, e4);

    for (int k = 0; k < 4; ++k) {
        int i = blockIdx.x * 4 + k;
        float4 wri = ld4<BF16>(wih, (size_t)(i        ) * H + e4);
        float4 wzi = ld4<BF16>(wih, (size_t)(H + i    ) * H + e4);
        float4 wni = ld4<BF16>(wih, (size_t)(2 * H + i) * H + e4);
        float4 wrh = ld4<BF16>(whh, (size_t)(i        ) * H + e4);
        float4 wzh = ld4<BF16>(whh, (size_t)(H + i    ) * H + e4);
        float4 wnh = ld4<BF16>(whh, (size_t)(2 * H + i) * H + e4);

        float a = wri.x * xv.x + wri.y * xv.y + wri.z * xv.z + wri.w * xv.w
                + wrh.x * hv.x + wrh.y * hv.y + wrh.z * hv.z + wrh.w * hv.w;
        float b = wzi.x * xv.x + wzi.y * xv.y + wzi.z * xv.z + wzi.w * xv.w
                + wzh.x * hv.x + wzh.y * hv.y + wzh.z * hv.z + wzh.w * hv.w;
        float c = wni.x * xv.x + wni.y * xv.y + wni.z * xv.z + wni.w * xv.w;
        float d = wnh.x * hv.x + wnh.y * hv.y + wnh.z * hv.z + wnh.w * hv.w;

        #pragma unroll
        for (int off = 32; off; off >>= 1) {
            a += __shfl_xor(a, off);
            b += __shfl_xor(b, off);
            c += __shfl_xor(c, off);
            d += __shfl_xor(d, off);
        }
        if (lane == 0) {
            float r = 1.f / (1.f + __expf(-(a + ld1<BF16>(bih, i) + ld1<BF16>(bhh, i))));
            float z = 1.f / (1.f + __expf(-(b + ld1<BF16>(bih, H + i) + ld1<BF16>(bhh, H + i))));
            float n = tanhf(c + ld1<BF16>(bih, 2 * H + i) + r * (d + ld1<BF16>(bhh, 2 * H + i)));
            float hold = ld1<BF16>(hprev, i);
            float hn = (1.f - z) * n + z * hold;
            xout[i] = hn;
            st<BF16>(hout, 0 + i, hn);
        }
    }
}

// ---------------- K6: logits GEMV + per-block online softmax partials ----------------
// Rebuilt for occupancy+ILP: 512 blocks x 256 thr = 2048 waves; each wave is two
// 32-lane row-groups (16B/lane spans a full bf16 row); 4 rows in flight per thread.
// Raw logits stashed in out[OUT_LOGP] (bf16 path: rounded; fp32 path: exact).
template<bool BF16>
__global__ __launch_bounds__(256) void k_logits(
    const void* __restrict__ out_w, const void* __restrict__ out_b,
    const float* __restrict__ xin, float* __restrict__ ws,
    void* __restrict__ out)
{
    if ((ws[WS_FLAG] > 0.5f) != BF16) return;
    int tid  = threadIdx.x;
    int wv   = (blockIdx.x << 2) | (tid >> 6);   // global wave id, 0..2047
    int lane = tid & 63;
    int l32  = lane & 31;
    int half = lane >> 5;

    // x fragment: 8 consecutive elements per lane (row-group covers 32*8=256)
    float xf[8];
    {
        const float4* xp = (const float4*)(xin + l32 * 8);
        float4 a = xp[0], b = xp[1];
        xf[0] = a.x; xf[1] = a.y; xf[2] = a.z; xf[3] = a.w;
        xf[4] = b.x; xf[5] = b.y; xf[6] = b.z; xf[7] = b.w;
    }

    float m = -1e30f, s = 0.f;
    const int r0 = wv * 2 + half;                 // 0..4095
    for (int r = r0; r < VOCAB; r += 4 * LOGITS_STRIDE) {
        int r1 = r + LOGITS_STRIDE;
        int r2 = r + 2 * LOGITS_STRIDE;
        int r3 = r + 3 * LOGITS_STRIDE;
        bool h1 = r1 < VOCAB, h2 = r2 < VOCAB, h3 = r3 < VOCAB;

        // issue all independent loads first (4 x 16B weight + 4 bias scalars)
        float w0[8], w1[8], w2[8], w3[8];
        float b0 = 0.f, b1 = 0.f, b2 = 0.f, b3 = 0.f;
        ld8<BF16>(out_w, (size_t)r * H + l32 * 8, w0);
        b0 = ld1<BF16>(out_b, r);
        if (h1) { ld8<BF16>(out_w, (size_t)r1 * H + l32 * 8, w1); b1 = ld1<BF16>(out_b, r1); }
        if (h2) { ld8<BF16>(out_w, (size_t)r2 * H + l32 * 8, w2); b2 = ld1<BF16>(out_b, r2); }
        if (h3) { ld8<BF16>(out_w, (size_t)r3 * H + l32 * 8, w3); b3 = ld1<BF16>(out_b, r3); }

        float v0 = w0[0]*xf[0]+w0[1]*xf[1]+w0[2]*xf[2]+w0[3]*xf[3]
                 + w0[4]*xf[4]+w0[5]*xf[5]+w0[6]*xf[6]+w0[7]*xf[7];
        float v1 = h1 ? (w1[0]*xf[0]+w1[1]*xf[1]+w1[2]*xf[2]+w1[3]*xf[3]
                       + w1[4]*xf[4]+w1[5]*xf[5]+w1[6]*xf[6]+w1[7]*xf[7]) : 0.f;
        float v2 = h2 ? (w2[0]*xf[0]+w2[1]*xf[1]+w2[2]*xf[2]+w2[3]*xf[3]
                       + w2[4]*xf[4]+w2[5]*xf[5]+w2[6]*xf[6]+w2[7]*xf[7]) : 0.f;
        float v3 = h3 ? (w3[0]*xf[0]+w3[1]*xf[1]+w3[2]*xf[2]+w3[3]*xf[3]
                       + w3[4]*xf[4]+w3[5]*xf[5]+w3[6]*xf[6]+w3[7]*xf[7]) : 0.f;

        // interleaved 32-lane butterfly (xor<32 stays within each half-wave)
        #pragma unroll
        for (int off = 16; off; off >>= 1) {
            v0 += __shfl_xor(v0, off);
            v1 += __shfl_xor(v1, off);
            v2 += __shfl_xor(v2, off);
            v3 += __shfl_xor(v3, off);
        }
        v0 += b0; v1 += b1; v2 += b2; v3 += b3;

        if (l32 == 0) {
            st<BF16>(out, OUT_LOGP + r, v0);
            if (h1) st<BF16>(out, OUT_LOGP + r1, v1);
            if (h2) st<BF16>(out, OUT_LOGP + r2, v2);
            if (h3) st<BF16>(out, OUT_LOGP + r3, v3);
        }

        { float mn = fmaxf(m, v0); s = s * __expf(m - mn) + __expf(v0 - mn); m = mn; }
        if (h1) { float mn = fmaxf(m, v1); s = s * __expf(m - mn) + __expf(v1 - mn); m = mn; }
        if (h2) { float mn = fmaxf(m, v2); s = s * __expf(m - mn) + __expf(v2 - mn); m = mn; }
        if (h3) { float mn = fmaxf(m, v3); s = s * __expf(m - mn) + __expf(v3 - mn); m = mn; }
    }

    // merge the two half-waves (all lanes in a half hold identical m,s)
    {
        float mo = __shfl_xor(m, 32), so = __shfl_xor(s, 32);
        float M = fmaxf(m, mo);
        s = s * __expf(m - M) + so * __expf(mo - M);
        m = M;
    }

    // block-level merge of 4 waves -> one partial per block (512 total)
    __shared__ float bm[4], bs[4];
    if (lane == 0) { bm[tid >> 6] = m; bs[tid >> 6] = s; }
    __syncthreads();
    if (tid == 0) {
        float M01 = fmaxf(bm[0], bm[1]);
        float S01 = bs[0] * __expf(bm[0] - M01) + bs[1] * __expf(bm[1] - M01);
        float M23 = fmaxf(bm[2], bm[3]);
        float S23 = bs[2] * __expf(bm[2] - M23) + bs[3] * __expf(bm[3] - M23);
        float Mx = fmaxf(M01, M23);
        float S  = S01 * __expf(M01 - Mx) + S23 * __expf(M23 - Mx);
        ws[WS_PM + blockIdx.x] = Mx;
        ws[WS_PS + blockIdx.x] = S;
    }
}

// ---------------- K7: combine partials (redundant per block) + rewrite logp ----------------
template<bool BF16>
__global__ __launch_bounds__(256) void k_logsoftmax(
    const float* __restrict__ ws, void* __restrict__ out)
{
    if ((ws[WS_FLAG] > 0.5f) != BF16) return;
    __shared__ float sm[256], ss[256];
    int t = threadIdx.x;
    float m1 = ws[WS_PM + t],       s1 = ws[WS_PS + t];
    float m2 = ws[WS_PM + 256 + t], s2 = ws[WS_PS + 256 + t];
    float M = fmaxf(m1, m2);
    float S = s1 * __expf(m1 - M) + s2 * __expf(m2 - M);
    sm[t] = M; ss[t] = S; __syncthreads();
    for (int off = 128; off; off >>= 1) {
        if (t < off) {
            float ma = sm[t], mb = sm[t + off];
            float Mx = fmaxf(ma, mb);
            ss[t] = ss[t] * __expf(ma - Mx) + ss[t + off] * __expf(mb - Mx);
            sm[t] = Mx;
        }
        __syncthreads();
    }
    float c = sm[0] + __logf(ss[0]);
    for (int r = blockIdx.x * blockDim.x + t; r < VOCAB; r += gridDim.x * blockDim.x) {
        float v = BF16 ? bf2f(((const u16*)out)[OUT_LOGP + r])
                       : ((const float*)out)[OUT_LOGP + r];
        st<BF16>(out, OUT_LOGP + r, v - c);
    }
}

template<bool BF16>
static void run_pipeline(const int* tok, void* const* d_in, float* ws, void* out,
                         hipStream_t stream) {
    const void* hidden = d_in[1];
    const void* enc    = d_in[2];
    const void* emb    = d_in[3];
    const void* attn_w = d_in[4];
    const void* attn_b = d_in[5];
    const void* comb_w = d_in[6];
    const void* comb_b = d_in[7];
    const char* gwih   = (const char*)d_in[8];
    const char* gwhh   = (const char*)d_in[9];
    const char* gbih   = (const char*)d_in[10];
    const char* gbhh   = (const char*)d_in[11];
    const void* out_w  = d_in[12];
    const void* out_b  = d_in[13];
    size_t es = BF16 ? 2 : 4;   // element size in bytes

    k_attn_score<BF16><<<dim3(32), dim3(64), 0, stream>>>(tok, emb, hidden, attn_w, attn_b, ws);
    k_softmax<BF16><<<dim3(1), dim3(256), 0, stream>>>(ws, out);
    k_attn_apply<BF16><<<dim3(16), dim3(256), 0, stream>>>(enc, ws);
    k_comb<BF16><<<dim3(32), dim3(64), 0, stream>>>(tok, emb, comb_w, comb_b, ws);

    for (int l = 0; l < NLAYERS; ++l) {
        float* xin  = ws + ((l & 1) ? WS_X1 : WS_X0);
        float* xout = ws + ((l & 1) ? WS_X0 : WS_X1);
        void* hout = (void*)((char*)out + (OUT_HID + l * H) * es);
        const void* hprev = (const void*)((const char*)d_in[1] + (size_t)l * H * es);
        k_gru<BF16><<<dim3(64), dim3(64), 0, stream>>>(
            gwih + (size_t)l * 3 * H * H * es, gwhh + (size_t)l * 3 * H * H * es,
            gbih + (size_t)l * 3 * H * es,     gbhh + (size_t)l * 3 * H * es,
            hprev, xin, xout, hout, ws);
    }
    k_logits<BF16><<<dim3(LOGITS_BLOCKS), dim3(256), 0, stream>>>(out_w, out_b, ws + WS_X0, ws, out);
    k_logsoftmax<BF16><<<dim3(128), dim3(256), 0, stream>>>(ws, out);
}

extern "C" void kernel_launch(void* const* d_in, const int* in_sizes, int n_in,
                              void* d_out, int out_size, void* d_ws, size_t ws_size,
                              hipStream_t stream) {
    const int* tok = (const int*)d_in[0];
    float* ws = (float*)d_ws;

    k_sniff<<<dim3(1), dim3(64), 0, stream>>>(d_in[3], ws);
    run_pipeline<true>(tok, d_in, ws, d_out, stream);   // bf16 variant (self-gated)
    run_pipeline<false>(tok, d_in, ws, d_out, stream);  // fp32 variant (self-gated)
}